// Round 7
// baseline (2190.719 us; speedup 1.0000x reference)
//
#include <hip/hip_runtime.h>
#include <math.h>

#define BATCH 4
#define CIN 64
#define HW 256
#define NPIX 65536       // 256*256
#define OC 192
#define TH 294
#define PS2 49
#define NWIN 36          // 6*6 windows per batch
#define WCPB 2304        // window-channels per batch (36*64)
#define C2N 2401         // 49*49 elements per window-channel
#define WSTR 52          // LDS row stride for K/V tile
#define WBUF 2600        // per-wave LDS floats (49*52 tile + 49 ink + pad)

// ---------------- K1: 1x1 conv (qkv) as LDS-tiled GEMM ----------------------
__global__ __launch_bounds__(256)
void k_qkv1x1(const float* __restrict__ x, const float* __restrict__ w,
              float* __restrict__ A) {
    __shared__ float wT[64][64];     // wT[c][o]
    __shared__ float xs[64][256];    // xs[c][px]
    x += (size_t)blockIdx.z * CIN * NPIX;
    A += (size_t)blockIdx.z * OC * NPIX;
    const int tid = threadIdx.x;
    const int pxbase = blockIdx.x * 256;
    const int ocbase = blockIdx.y * 64;

    for (int idx = tid; idx < 1024; idx += 256) {
        int o = idx >> 4, c4 = idx & 15;
        float4 v = *reinterpret_cast<const float4*>(w + (size_t)(ocbase + o) * CIN + c4 * 4);
        wT[c4 * 4 + 0][o] = v.x; wT[c4 * 4 + 1][o] = v.y;
        wT[c4 * 4 + 2][o] = v.z; wT[c4 * 4 + 3][o] = v.w;
    }
    for (int idx = tid; idx < 4096; idx += 256) {
        int c = idx >> 6, p4 = idx & 63;
        float4 v = *reinterpret_cast<const float4*>(x + (size_t)c * NPIX + pxbase + p4 * 4);
        *reinterpret_cast<float4*>(&xs[c][p4 * 4]) = v;
    }
    __syncthreads();

    const int tx = tid & 15, ty = tid >> 4;
    float acc[4][16];
    #pragma unroll
    for (int a = 0; a < 4; ++a)
        #pragma unroll
        for (int b = 0; b < 16; ++b) acc[a][b] = 0.f;

    #pragma unroll 4
    for (int k = 0; k < 64; ++k) {
        float4 wv = *reinterpret_cast<const float4*>(&wT[k][ty * 4]);
        float wr[4] = {wv.x, wv.y, wv.z, wv.w};
        float xv[16];
        #pragma unroll
        for (int i = 0; i < 4; ++i) {
            float4 v = *reinterpret_cast<const float4*>(&xs[k][tx * 4 + i * 64]);
            xv[i * 4 + 0] = v.x; xv[i * 4 + 1] = v.y;
            xv[i * 4 + 2] = v.z; xv[i * 4 + 3] = v.w;
        }
        #pragma unroll
        for (int a = 0; a < 4; ++a)
            #pragma unroll
            for (int b = 0; b < 16; ++b)
                acc[a][b] = fmaf(wr[a], xv[b], acc[a][b]);
    }

    #pragma unroll
    for (int a = 0; a < 4; ++a) {
        float* Ap = A + (size_t)(ocbase + ty * 4 + a) * NPIX + pxbase;
        #pragma unroll
        for (int i = 0; i < 4; ++i)
            *reinterpret_cast<float4*>(Ap + tx * 4 + i * 64) =
                make_float4(acc[a][i * 4 + 0], acc[a][i * 4 + 1],
                            acc[a][i * 4 + 2], acc[a][i * 4 + 3]);
    }
}

// ---------------- K2: depthwise 3x3, 4 pixels/thread ------------------------
__global__ __launch_bounds__(256)
void k_dw3x3(const float* __restrict__ A, const float* __restrict__ dwv,
             float* __restrict__ Bf) {
    A  += (size_t)blockIdx.z * OC * NPIX;
    Bf += (size_t)blockIdx.z * OC * NPIX;
    int gid = blockIdx.x * 256 + threadIdx.x;
    int ch = gid >> 14;
    int q  = gid & 16383;
    int y  = q >> 6;
    int x4 = (q & 63) << 2;
    const float* Ap = A + (size_t)ch * NPIX;
    float wv[9];
    #pragma unroll
    for (int i = 0; i < 9; ++i) wv[i] = dwv[ch * 9 + i];
    float acc0 = 0.f, acc1 = 0.f, acc2 = 0.f, acc3 = 0.f;
    #pragma unroll
    for (int ky = 0; ky < 3; ++ky) {
        int yy = y + ky - 1;
        if (yy < 0 || yy >= HW) continue;
        const float* row = Ap + yy * HW;
        float cv[6];
        #pragma unroll
        for (int t = 0; t < 6; ++t) {
            int xx = x4 - 1 + t;
            cv[t] = (xx >= 0 && xx < HW) ? row[xx] : 0.f;
        }
        #pragma unroll
        for (int kx = 0; kx < 3; ++kx) {
            float wk = wv[ky * 3 + kx];
            acc0 = fmaf(cv[0 + kx], wk, acc0);
            acc1 = fmaf(cv[1 + kx], wk, acc1);
            acc2 = fmaf(cv[2 + kx], wk, acc2);
            acc3 = fmaf(cv[3 + kx], wk, acc3);
        }
    }
    *reinterpret_cast<float4*>(Bf + (size_t)ch * NPIX + y * HW + x4) =
        make_float4(acc0, acc1, acc2, acc3);
}

// ---------------- K3: wave-per-(window,channel) attention, no shuffles ------
// lane = query row i; jj-loop over keys with LDS broadcast.
// K and V time-share one 10.4 KB tile per wave (same-wave LDS ops retire in
// program order -> WAR safe). Output stored transposed-coalesced into C2:
// C2[wc][j*49 + i] = O[i][j].
__global__ __launch_bounds__(256)
void k_attn(const float* __restrict__ Bf, float* __restrict__ C2) {
    __shared__ float buf[4][WBUF];
    Bf += (size_t)blockIdx.z * OC * NPIX;
    C2 += (size_t)blockIdx.z * WCPB * C2N;
    const int tid  = threadIdx.x;
    const int wv   = tid >> 6, lane = tid & 63;
    const int wc   = blockIdx.x * 4 + wv;       // [0, 2304)
    const int ch   = wc & 63;
    const int win  = wc >> 6;
    const int xw   = win / 6, yw = win - xw * 6;
    const float* qb = Bf + (size_t)ch * NPIX;
    const float* kb = qb + (size_t)64  * NPIX;
    const float* vb = qb + (size_t)128 * NPIX;
    float* W = buf[wv];
    const float scale = 255.0f / 293.0f;        // align_corners=True, 256->294
    const int l  = min(lane, PS2 - 1);
    const int h  = l % 7, pw = l / 7;
    const bool act = (lane < PS2);

    // per-lane bilinear tables; row i=l of window matrix covers spatial
    // pixels rl=(t%7)*7 + l%7, cl=(l/7)*7 + t/7 for t=0..48
    int   y0i[7], y1i[7], x0i[7], x1i[7];
    float lyf[7], lxf[7];
    #pragma unroll
    for (int ph = 0; ph < 7; ++ph) {
        float sy = (float)(xw * PS2 + ph * 7 + h) * scale;
        int y0 = (int)sy;
        lyf[ph] = sy - (float)y0;
        y0i[ph] = y0 * HW;
        y1i[ph] = min(y0 + 1, HW - 1) * HW;
    }
    #pragma unroll
    for (int w_ = 0; w_ < 7; ++w_) {
        float sx = (float)(yw * PS2 + pw * 7 + w_) * scale;
        int x0 = (int)sx;
        lxf[w_] = sx - (float)x0;
        x0i[w_] = x0;
        x1i[w_] = min(x0 + 1, HW - 1);
    }

    // gather: Q row -> regs, K row -> LDS, norms inline
    float qreg[PS2];
    float qss = 0.f, kss = 0.f;
    #pragma unroll
    for (int t = 0; t < PS2; ++t) {
        const int ph = t % 7, w_ = t / 7;
        int a00 = y0i[ph] + x0i[w_], a01 = y0i[ph] + x1i[w_];
        int a10 = y1i[ph] + x0i[w_], a11 = y1i[ph] + x1i[w_];
        float ly = lyf[ph], lx = lxf[w_];
        float w00 = (1.f - ly) * (1.f - lx), w01 = (1.f - ly) * lx;
        float w10 = ly * (1.f - lx),         w11 = ly * lx;
        float qv = qb[a00] * w00 + qb[a01] * w01 + qb[a10] * w10 + qb[a11] * w11;
        float kv = kb[a00] * w00 + kb[a01] * w01 + kb[a10] * w10 + kb[a11] * w11;
        qreg[t] = qv;
        qss = fmaf(qv, qv, qss);
        kss = fmaf(kv, kv, kss);
        if (act) W[l * WSTR + t] = kv;
    }
    float inq = 1.f / fmaxf(sqrtf(qss), 1e-12f);
    if (act) W[PS2 * WSTR + l] = 1.f / fmaxf(sqrtf(kss), 1e-12f);  // ink[l]

    // pass 1: S row in registers, lane-local softmax (no cross-lane ops)
    float s[PS2];
    float m = -INFINITY;
    #pragma unroll
    for (int jj = 0; jj < PS2; ++jj) {
        float ink = W[PS2 * WSTR + jj];
        float d0 = 0.f, d1 = 0.f;
        #pragma unroll
        for (int u = 0; u < 12; ++u) {
            float4 kk = *reinterpret_cast<const float4*>(&W[jj * WSTR + u * 4]);
            d0 = fmaf(qreg[u * 4 + 0], kk.x, d0);
            d1 = fmaf(qreg[u * 4 + 1], kk.y, d1);
            d0 = fmaf(qreg[u * 4 + 2], kk.z, d0);
            d1 = fmaf(qreg[u * 4 + 3], kk.w, d1);
        }
        d0 = fmaf(qreg[48], W[jj * WSTR + 48], d0);
        float sv = (d0 + d1) * ink * inq;
        s[jj] = sv;
        m = fmaxf(m, sv);
    }
    float ssum = 0.f;
    #pragma unroll
    for (int jj = 0; jj < PS2; ++jj) {
        s[jj] = __expf(s[jj] - m);
        ssum += s[jj];
    }
    float rs = 1.f / ssum;

    // re-gather V over the K tile (same-wave program order: K reads done)
    #pragma unroll
    for (int t = 0; t < PS2; ++t) {
        const int ph = t % 7, w_ = t / 7;
        int a00 = y0i[ph] + x0i[w_], a01 = y0i[ph] + x1i[w_];
        int a10 = y1i[ph] + x0i[w_], a11 = y1i[ph] + x1i[w_];
        float ly = lyf[ph], lx = lxf[w_];
        float w00 = (1.f - ly) * (1.f - lx), w01 = (1.f - ly) * lx;
        float w10 = ly * (1.f - lx),         w11 = ly * lx;
        float vvv = vb[a00] * w00 + vb[a01] * w01 + vb[a10] * w10 + vb[a11] * w11;
        if (act) W[l * WSTR + t] = vvv;
    }

    // pass 3: O = P @ V via broadcast V rows
    float o[PS2];
    #pragma unroll
    for (int t = 0; t < PS2; ++t) o[t] = 0.f;
    #pragma unroll
    for (int jj = 0; jj < PS2; ++jj) {
        float p = s[jj];
        #pragma unroll
        for (int u = 0; u < 12; ++u) {
            float4 vv = *reinterpret_cast<const float4*>(&W[jj * WSTR + u * 4]);
            o[u * 4 + 0] = fmaf(p, vv.x, o[u * 4 + 0]);
            o[u * 4 + 1] = fmaf(p, vv.y, o[u * 4 + 1]);
            o[u * 4 + 2] = fmaf(p, vv.z, o[u * 4 + 2]);
            o[u * 4 + 3] = fmaf(p, vv.w, o[u * 4 + 3]);
        }
        o[48] = fmaf(p, W[jj * WSTR + 48], o[48]);
    }

    // store: C2[wc][t*49 + l] = O[l][t]  (consecutive lanes -> consecutive addr)
    float* cp = C2 + (size_t)wc * C2N;
    #pragma unroll
    for (int t = 0; t < PS2; ++t)
        if (act) cp[t * PS2 + l] = o[t] * rs;
}

// ------- K4: bilinear down 294->256 + proj, reading window-native C2 --------
// C2 holds O transposed: element (row i, col t) of window wc is at
// C2[wc*C2N + t*49 + i]  — must match k_attn's store.
__device__ __forceinline__ int c2_base(int yy, int xx) {
    int xw = yy / PS2, rl = yy - xw * PS2;
    int yw = xx / PS2, cl = xx - yw * PS2;
    int i = (cl / 7) * 7 + rl % 7;      // matrix row
    int t = (cl % 7) * 7 + rl / 7;      // matrix col
    return ((xw * 6 + yw) * 64) * C2N + t * PS2 + i;
}

__global__ __launch_bounds__(256)
void k_proj(const float* __restrict__ C2, const float* __restrict__ pw,
            float* __restrict__ out) {
    C2  += (size_t)blockIdx.z * WCPB * C2N;
    out += (size_t)blockIdx.z * CIN * NPIX;
    int gid  = blockIdx.x * 256 + threadIdx.x;
    int half = gid >> 16;
    int p    = gid & 65535;
    int y = p >> 8, xx = p & 255;
    const float sc = 294.0f / 256.0f;
    float sy = fmaxf((y + 0.5f) * sc - 0.5f, 0.f);
    float sx = fmaxf((xx + 0.5f) * sc - 0.5f, 0.f);
    int y0 = (int)sy, x0 = (int)sx;
    float ly = sy - y0, lx = sx - x0;
    int y1 = min(y0 + 1, TH - 1), x1 = min(x0 + 1, TH - 1);
    float w00 = (1.f - ly) * (1.f - lx), w01 = (1.f - ly) * lx;
    float w10 = ly * (1.f - lx),         w11 = ly * lx;
    int b00 = c2_base(y0, x0), b01 = c2_base(y0, x1);
    int b10 = c2_base(y1, x0), b11 = c2_base(y1, x1);
    float rv[CIN];
    #pragma unroll
    for (int c = 0; c < CIN; ++c) {
        int co = c * C2N;
        rv[c] = C2[b00 + co] * w00 + C2[b01 + co] * w01 +
                C2[b10 + co] * w10 + C2[b11 + co] * w11;
    }
    float* op = out + (size_t)half * 32 * NPIX + p;
    for (int o = 0; o < 32; ++o) {
        const float* wr = pw + (half * 32 + o) * CIN;
        float acc = 0.f;
        #pragma unroll
        for (int c = 0; c < CIN; ++c) acc = fmaf(rv[c], wr[c], acc);
        op[(size_t)o * NPIX] = acc;
    }
}

// ---------------- launch --------------------------------------------------
extern "C" void kernel_launch(void* const* d_in, const int* in_sizes, int n_in,
                              void* d_out, int out_size, void* d_ws, size_t ws_size,
                              hipStream_t stream) {
    const float* x   = (const float*)d_in[0];
    const float* qw  = (const float*)d_in[1];
    const float* dwv = (const float*)d_in[2];
    const float* pw  = (const float*)d_in[3];
    float* out = (float*)d_out;

    const size_t perAB = (size_t)OC * NPIX;
    const size_t needBig = (size_t)2 * BATCH * perAB * sizeof(float);  // 384 MB

    if (ws_size >= needBig) {
        float* A = (float*)d_ws;
        float* B = A + BATCH * perAB;
        float* C = A;   // C2 aliases A (A dead after k_dw3x3); 9.2 MB/batch
        hipLaunchKernelGGL(k_qkv1x1, dim3(256, 3, BATCH),   dim3(256), 0, stream, x, qw, A);
        hipLaunchKernelGGL(k_dw3x3,  dim3(12288, 1, BATCH), dim3(256), 0, stream, A, dwv, B);
        hipLaunchKernelGGL(k_attn,   dim3(576, 1, BATCH),   dim3(256), 0, stream, B, C);
        hipLaunchKernelGGL(k_proj,   dim3(512, 1, BATCH),   dim3(256), 0, stream, C, pw, out);
    } else {
        float* A = (float*)d_ws;
        float* B = A + perAB;
        float* C = A;
        for (int b = 0; b < BATCH; ++b) {
            const float* xb = x + (size_t)b * CIN * NPIX;
            float* ob = out + (size_t)b * CIN * NPIX;
            hipLaunchKernelGGL(k_qkv1x1, dim3(256, 3, 1),   dim3(256), 0, stream, xb, qw, A);
            hipLaunchKernelGGL(k_dw3x3,  dim3(12288, 1, 1), dim3(256), 0, stream, A, dwv, B);
            hipLaunchKernelGGL(k_attn,   dim3(576, 1, 1),   dim3(256), 0, stream, B, C);
            hipLaunchKernelGGL(k_proj,   dim3(512, 1, 1),   dim3(256), 0, stream, C, pw, ob);
        }
    }
}

// Round 8
// 1223.358 us; speedup vs baseline: 1.7907x; 1.7907x over previous
//
#include <hip/hip_runtime.h>
#include <math.h>

#define BATCH 4
#define CIN 64
#define HW 256
#define NPIX 65536       // 256*256
#define OC 192
#define TH 294
#define PS2 49
#define NWIN 36          // 6*6 windows per batch
#define WCPB 2304        // window-channels per batch (36*64)
#define C2N 2401         // 49*49 elements per window-channel
#define KSTR 52          // K/V tile row stride (52*4B = 208B, 16B-aligned)
#define KOFF 0
#define VOFF (PS2 * KSTR)        // 2548
#define IOFF (2 * PS2 * KSTR)    // 5096
#define WVBUF 5184               // per-wave LDS floats

// ---------------- K1: 1x1 conv (qkv) as LDS-tiled GEMM ----------------------
__global__ __launch_bounds__(256)
void k_qkv1x1(const float* __restrict__ x, const float* __restrict__ w,
              float* __restrict__ A) {
    __shared__ float wT[64][64];     // wT[c][o]
    __shared__ float xs[64][256];    // xs[c][px]
    x += (size_t)blockIdx.z * CIN * NPIX;
    A += (size_t)blockIdx.z * OC * NPIX;
    const int tid = threadIdx.x;
    const int pxbase = blockIdx.x * 256;
    const int ocbase = blockIdx.y * 64;

    for (int idx = tid; idx < 1024; idx += 256) {
        int o = idx >> 4, c4 = idx & 15;
        float4 v = *reinterpret_cast<const float4*>(w + (size_t)(ocbase + o) * CIN + c4 * 4);
        wT[c4 * 4 + 0][o] = v.x; wT[c4 * 4 + 1][o] = v.y;
        wT[c4 * 4 + 2][o] = v.z; wT[c4 * 4 + 3][o] = v.w;
    }
    for (int idx = tid; idx < 4096; idx += 256) {
        int c = idx >> 6, p4 = idx & 63;
        float4 v = *reinterpret_cast<const float4*>(x + (size_t)c * NPIX + pxbase + p4 * 4);
        *reinterpret_cast<float4*>(&xs[c][p4 * 4]) = v;
    }
    __syncthreads();

    const int tx = tid & 15, ty = tid >> 4;
    float acc[4][16];
    #pragma unroll
    for (int a = 0; a < 4; ++a)
        #pragma unroll
        for (int b = 0; b < 16; ++b) acc[a][b] = 0.f;

    #pragma unroll 4
    for (int k = 0; k < 64; ++k) {
        float4 wv = *reinterpret_cast<const float4*>(&wT[k][ty * 4]);
        float wr[4] = {wv.x, wv.y, wv.z, wv.w};
        float xv[16];
        #pragma unroll
        for (int i = 0; i < 4; ++i) {
            float4 v = *reinterpret_cast<const float4*>(&xs[k][tx * 4 + i * 64]);
            xv[i * 4 + 0] = v.x; xv[i * 4 + 1] = v.y;
            xv[i * 4 + 2] = v.z; xv[i * 4 + 3] = v.w;
        }
        #pragma unroll
        for (int a = 0; a < 4; ++a)
            #pragma unroll
            for (int b = 0; b < 16; ++b)
                acc[a][b] = fmaf(wr[a], xv[b], acc[a][b]);
    }

    #pragma unroll
    for (int a = 0; a < 4; ++a) {
        float* Ap = A + (size_t)(ocbase + ty * 4 + a) * NPIX + pxbase;
        #pragma unroll
        for (int i = 0; i < 4; ++i)
            *reinterpret_cast<float4*>(Ap + tx * 4 + i * 64) =
                make_float4(acc[a][i * 4 + 0], acc[a][i * 4 + 1],
                            acc[a][i * 4 + 2], acc[a][i * 4 + 3]);
    }
}

// ---------------- K2: depthwise 3x3, 4 pixels/thread ------------------------
__global__ __launch_bounds__(256)
void k_dw3x3(const float* __restrict__ A, const float* __restrict__ dwv,
             float* __restrict__ Bf) {
    A  += (size_t)blockIdx.z * OC * NPIX;
    Bf += (size_t)blockIdx.z * OC * NPIX;
    int gid = blockIdx.x * 256 + threadIdx.x;
    int ch = gid >> 14;
    int q  = gid & 16383;
    int y  = q >> 6;
    int x4 = (q & 63) << 2;
    const float* Ap = A + (size_t)ch * NPIX;
    float wv[9];
    #pragma unroll
    for (int i = 0; i < 9; ++i) wv[i] = dwv[ch * 9 + i];
    float acc0 = 0.f, acc1 = 0.f, acc2 = 0.f, acc3 = 0.f;
    #pragma unroll
    for (int ky = 0; ky < 3; ++ky) {
        int yy = y + ky - 1;
        if (yy < 0 || yy >= HW) continue;
        const float* row = Ap + yy * HW;
        float cv[6];
        #pragma unroll
        for (int t = 0; t < 6; ++t) {
            int xx = x4 - 1 + t;
            cv[t] = (xx >= 0 && xx < HW) ? row[xx] : 0.f;
        }
        #pragma unroll
        for (int kx = 0; kx < 3; ++kx) {
            float wk = wv[ky * 3 + kx];
            acc0 = fmaf(cv[0 + kx], wk, acc0);
            acc1 = fmaf(cv[1 + kx], wk, acc1);
            acc2 = fmaf(cv[2 + kx], wk, acc2);
            acc3 = fmaf(cv[3 + kx], wk, acc3);
        }
    }
    *reinterpret_cast<float4*>(Bf + (size_t)ch * NPIX + y * HW + x4) =
        make_float4(acc0, acc1, acc2, acc3);
}

// ---------------- K3: fused single-pass attention, lane = query row ---------
// |S|<=1 (cosine) => softmax without max subtraction => no s[] array.
// Live registers: qreg[49] + o[49] (~120 VGPR). K,V tiles in per-wave LDS.
__global__ __launch_bounds__(128)
void k_attn(const float* __restrict__ Bf, float* __restrict__ C2) {
    __shared__ float buf[2][WVBUF];
    Bf += (size_t)blockIdx.z * OC * NPIX;
    C2 += (size_t)blockIdx.z * WCPB * C2N;
    const int tid  = threadIdx.x;
    const int wvi  = tid >> 6, lane = tid & 63;
    const int wc   = blockIdx.x * 2 + wvi;      // [0, 2304)
    const int ch   = wc & 63;
    const int win  = wc >> 6;
    const int xw   = win / 6, yw = win - xw * 6;
    const float* qb = Bf + (size_t)ch * NPIX;
    const float* kb = qb + (size_t)64  * NPIX;
    const float* vb = qb + (size_t)128 * NPIX;
    float* W = buf[wvi];
    const float scale = 255.0f / 293.0f;        // align_corners=True, 256->294
    const int l  = min(lane, PS2 - 1);          // matrix row i
    const int fr = l % 7;                        // fine vertical component
    const int cc = l / 7;                        // coarse horizontal component
    const bool act = (lane < PS2);

    // per-lane bilinear tables; row i=l covers pixels
    // vertical=(t%7)*7 + l%7, horizontal=(l/7)*7 + t/7 for col t
    int   y0i[7], y1i[7], x0i[7], x1i[7];
    float lyf[7], lxf[7];
    #pragma unroll
    for (int a = 0; a < 7; ++a) {
        float sy = (float)(xw * PS2 + a * 7 + fr) * scale;
        int y0 = (int)sy;
        lyf[a] = sy - (float)y0;
        y0i[a] = y0 * HW;
        y1i[a] = min(y0 + 1, HW - 1) * HW;
        float sx = (float)(yw * PS2 + cc * 7 + a) * scale;
        int x0 = (int)sx;
        lxf[a] = sx - (float)x0;
        x0i[a] = x0;
        x1i[a] = min(x0 + 1, HW - 1);
    }

    // gather: Q row -> regs; K,V rows -> LDS; norms inline
    float qreg[PS2];
    float qss = 0.f, kss = 0.f;
    #pragma unroll
    for (int w_ = 0; w_ < 7; ++w_) {
        #pragma unroll
        for (int p_ = 0; p_ < 7; ++p_) {
            const int t = w_ * 7 + p_;
            int a00 = y0i[p_] + x0i[w_], a01 = y0i[p_] + x1i[w_];
            int a10 = y1i[p_] + x0i[w_], a11 = y1i[p_] + x1i[w_];
            float ly = lyf[p_], lx = lxf[w_];
            float w00 = (1.f - ly) * (1.f - lx), w01 = (1.f - ly) * lx;
            float w10 = ly * (1.f - lx),         w11 = ly * lx;
            float qv = qb[a00] * w00 + qb[a01] * w01 + qb[a10] * w10 + qb[a11] * w11;
            float kv = kb[a00] * w00 + kb[a01] * w01 + kb[a10] * w10 + kb[a11] * w11;
            float vv = vb[a00] * w00 + vb[a01] * w01 + vb[a10] * w10 + vb[a11] * w11;
            qreg[t] = qv;
            qss = fmaf(qv, qv, qss);
            kss = fmaf(kv, kv, kss);
            if (act) {
                W[KOFF + l * KSTR + t] = kv;
                W[VOFF + l * KSTR + t] = vv;
            }
        }
    }
    float inq = 1.f / fmaxf(sqrtf(qss), 1e-12f);
    if (act) W[IOFF + l] = 1.f / fmaxf(sqrtf(kss), 1e-12f);   // ink[l]

    // fused pass: p = exp(S) (no max shift; |S|<=1), accumulate O and sum
    float o[PS2];
    #pragma unroll
    for (int t = 0; t < PS2; ++t) o[t] = 0.f;
    float ssum = 0.f;
    #pragma unroll 7
    for (int jj = 0; jj < PS2; ++jj) {
        const float* kr = &W[KOFF + jj * KSTR];
        float d0 = 0.f, d1 = 0.f;
        #pragma unroll
        for (int u = 0; u < 12; ++u) {
            float4 kk = *reinterpret_cast<const float4*>(&kr[u * 4]);
            d0 = fmaf(qreg[u * 4 + 0], kk.x, d0);
            d1 = fmaf(qreg[u * 4 + 1], kk.y, d1);
            d0 = fmaf(qreg[u * 4 + 2], kk.z, d0);
            d1 = fmaf(qreg[u * 4 + 3], kk.w, d1);
        }
        d0 = fmaf(qreg[48], kr[48], d0);
        float p = __expf((d0 + d1) * W[IOFF + jj] * inq);
        ssum += p;
        const float* vr = &W[VOFF + jj * KSTR];
        #pragma unroll
        for (int u = 0; u < 12; ++u) {
            float4 vv4 = *reinterpret_cast<const float4*>(&vr[u * 4]);
            o[u * 4 + 0] = fmaf(p, vv4.x, o[u * 4 + 0]);
            o[u * 4 + 1] = fmaf(p, vv4.y, o[u * 4 + 1]);
            o[u * 4 + 2] = fmaf(p, vv4.z, o[u * 4 + 2]);
            o[u * 4 + 3] = fmaf(p, vv4.w, o[u * 4 + 3]);
        }
        o[48] = fmaf(p, vr[48], o[48]);
    }
    float rs = 1.f / ssum;

    // store: C2[wc][t*49 + l] = O[l][t]  (consecutive lanes -> consecutive addr)
    float* cp = C2 + (size_t)wc * C2N;
    if (act) {
        #pragma unroll
        for (int t = 0; t < PS2; ++t)
            cp[t * PS2 + l] = o[t] * rs;
    }
}

// ------- K4: bilinear down 294->256 + proj, reading window-native C2 --------
// C2 holds O transposed: element (row i, col t) of window wc is at
// C2[wc*C2N + t*49 + i]  — must match k_attn's store.
__device__ __forceinline__ int c2_base(int yy, int xx) {
    int xw = yy / PS2, rl = yy - xw * PS2;
    int yw = xx / PS2, cl = xx - yw * PS2;
    int i = (cl / 7) * 7 + rl % 7;      // matrix row
    int t = (cl % 7) * 7 + rl / 7;      // matrix col
    return ((xw * 6 + yw) * 64) * C2N + t * PS2 + i;
}

__global__ __launch_bounds__(256)
void k_proj(const float* __restrict__ C2, const float* __restrict__ pw,
            float* __restrict__ out) {
    C2  += (size_t)blockIdx.z * WCPB * C2N;
    out += (size_t)blockIdx.z * CIN * NPIX;
    int gid  = blockIdx.x * 256 + threadIdx.x;
    int half = gid >> 16;
    int p    = gid & 65535;
    int y = p >> 8, xx = p & 255;
    const float sc = 294.0f / 256.0f;
    float sy = fmaxf((y + 0.5f) * sc - 0.5f, 0.f);
    float sx = fmaxf((xx + 0.5f) * sc - 0.5f, 0.f);
    int y0 = (int)sy, x0 = (int)sx;
    float ly = sy - y0, lx = sx - x0;
    int y1 = min(y0 + 1, TH - 1), x1 = min(x0 + 1, TH - 1);
    float w00 = (1.f - ly) * (1.f - lx), w01 = (1.f - ly) * lx;
    float w10 = ly * (1.f - lx),         w11 = ly * lx;
    int b00 = c2_base(y0, x0), b01 = c2_base(y0, x1);
    int b10 = c2_base(y1, x0), b11 = c2_base(y1, x1);
    float rv[CIN];
    #pragma unroll
    for (int c = 0; c < CIN; ++c) {
        int co = c * C2N;
        rv[c] = C2[b00 + co] * w00 + C2[b01 + co] * w01 +
                C2[b10 + co] * w10 + C2[b11 + co] * w11;
    }
    float* op = out + (size_t)half * 32 * NPIX + p;
    for (int o = 0; o < 32; ++o) {
        const float* wr = pw + (half * 32 + o) * CIN;
        float acc = 0.f;
        #pragma unroll
        for (int c = 0; c < CIN; ++c) acc = fmaf(rv[c], wr[c], acc);
        op[(size_t)o * NPIX] = acc;
    }
}

// ---------------- launch --------------------------------------------------
extern "C" void kernel_launch(void* const* d_in, const int* in_sizes, int n_in,
                              void* d_out, int out_size, void* d_ws, size_t ws_size,
                              hipStream_t stream) {
    const float* x   = (const float*)d_in[0];
    const float* qw  = (const float*)d_in[1];
    const float* dwv = (const float*)d_in[2];
    const float* pw  = (const float*)d_in[3];
    float* out = (float*)d_out;

    const size_t perAB = (size_t)OC * NPIX;
    const size_t needBig = (size_t)2 * BATCH * perAB * sizeof(float);  // 384 MB

    if (ws_size >= needBig) {
        float* A = (float*)d_ws;
        float* B = A + BATCH * perAB;
        float* C = A;   // C2 aliases A (A dead after k_dw3x3); 9.2 MB/batch
        hipLaunchKernelGGL(k_qkv1x1, dim3(256, 3, BATCH),   dim3(256), 0, stream, x, qw, A);
        hipLaunchKernelGGL(k_dw3x3,  dim3(12288, 1, BATCH), dim3(256), 0, stream, A, dwv, B);
        hipLaunchKernelGGL(k_attn,   dim3(1152, 1, BATCH),  dim3(128), 0, stream, B, C);
        hipLaunchKernelGGL(k_proj,   dim3(512, 1, BATCH),   dim3(256), 0, stream, C, pw, out);
    } else {
        float* A = (float*)d_ws;
        float* B = A + perAB;
        float* C = A;
        for (int b = 0; b < BATCH; ++b) {
            const float* xb = x + (size_t)b * CIN * NPIX;
            float* ob = out + (size_t)b * CIN * NPIX;
            hipLaunchKernelGGL(k_qkv1x1, dim3(256, 3, 1),   dim3(256), 0, stream, xb, qw, A);
            hipLaunchKernelGGL(k_dw3x3,  dim3(12288, 1, 1), dim3(256), 0, stream, A, dwv, B);
            hipLaunchKernelGGL(k_attn,   dim3(1152, 1, 1),  dim3(128), 0, stream, B, C);
            hipLaunchKernelGGL(k_proj,   dim3(512, 1, 1),   dim3(256), 0, stream, C, pw, ob);
        }
    }
}